// Round 6
// baseline (965.478 us; speedup 1.0000x reference)
//
#include <hip/hip_runtime.h>
#include <math.h>

#define TOKENS   8192
#define HIDDEN   7168
#define NEXPERT  256
#define NGROUP   8
#define TOPKG    4
#define TOPK     8
#define SCALE    2.5f

// GEMM tiling: 32 tokens x 128 experts per block, K-tile 64, split-K 2.
// grid (2 n, 256 m, 2 k) = 1024 blocks; LDS 40 KB -> 4 blocks/CU resident
// (16 waves/CU, 4 independent barrier domains -> latency hiding).
#define BM 32
#define BN 128
#define BK 64
#define KSPLIT 2
#define KPB (HIDDEN / KSPLIT)        // 3584
#define NT  (KPB / BK)               // 56
#define NKT (HIDDEN / BK)            // 112 k-tiles total
#define TILE_HALVES (2 * BN * BK)    // 16384 halves = 32 KB (hi 16K | lo 16K)
#define TILE_F4 (TILE_HALVES / 8)    // 2048 float4 per image tile
#define WIMG_HALVES ((size_t)2 * NKT * TILE_HALVES)            // 7.34 MB
#define WIMG_BYTES  (WIMG_HALVES * sizeof(_Float16))
#define PART_FLOATS ((size_t)KSPLIT * TOKENS * NEXPERT)        // 16.8 MB
#define PART_BYTES  (PART_FLOATS * sizeof(float))

typedef _Float16 half8 __attribute__((ext_vector_type(8)));
typedef _Float16 half4 __attribute__((ext_vector_type(4)));
typedef float    floatx4 __attribute__((ext_vector_type(4)));

// XOR swizzle in 16B (8-half) groups: row stride 64 halves = 128 B.
// Frag reads and staged writes <=2-way bank aliasing (free, m136);
// R3-R5 measured SQ_LDS_BANK_CONFLICT == 0 with this map.
__device__ __forceinline__ int swz(int r, int k) {
    return r * 64 + ((((k >> 3) ^ (r & 7)) << 3) | (k & 7));
}

__device__ __forceinline__ void cvt_store(_Float16* __restrict__ Hh,
                                          _Float16* __restrict__ Hl,
                                          int r, int k0, float4 v) {
    half4 h, l;
    h[0] = (_Float16)v.x; h[1] = (_Float16)v.y;
    h[2] = (_Float16)v.z; h[3] = (_Float16)v.w;
    l[0] = (_Float16)(v.x - (float)h[0]);
    l[1] = (_Float16)(v.y - (float)h[1]);
    l[2] = (_Float16)(v.z - (float)h[2]);
    l[3] = (_Float16)(v.w - (float)h[3]);
    const int a = swz(r, k0);
    *(half4*)&Hh[a] = h;
    *(half4*)&Hl[a] = l;
}

// ---------------------------------------------------------------------------
// zero d_out — FALLBACK path only (atomics need 0 init; d_out poisoned 0xAA)
// ---------------------------------------------------------------------------
__global__ __launch_bounds__(256) void zero_kernel(float* __restrict__ O) {
    const int i = blockIdx.x * 256 + threadIdx.x;
    *(float4*)&O[(size_t)i * 4] = float4{0.f, 0.f, 0.f, 0.f};
}

// ---------------------------------------------------------------------------
// Pre-pass: split W (fp32) into fp16 hi/lo laid out as the EXACT LDS image
// each GEMM block needs (pre-swizzled, hi 16KB | lo 16KB per k-tile).
// ---------------------------------------------------------------------------
__global__ __launch_bounds__(256) void wsplit_kernel(
    const float* __restrict__ W, _Float16* __restrict__ img)
{
    const int gid = blockIdx.x * 256 + threadIdx.x;      // 0 .. 458751
    const int r   = gid / (HIDDEN / 4);                  // expert 0..255
    const int k0  = (gid % (HIDDEN / 4)) * 4;
    const float4 v = *(const float4*)&W[(size_t)r * HIDDEN + k0];
    half4 h, l;
    h[0] = (_Float16)v.x; h[1] = (_Float16)v.y;
    h[2] = (_Float16)v.z; h[3] = (_Float16)v.w;
    l[0] = (_Float16)(v.x - (float)h[0]);
    l[1] = (_Float16)(v.y - (float)h[1]);
    l[2] = (_Float16)(v.z - (float)h[2]);
    l[3] = (_Float16)(v.w - (float)h[3]);
    const int nblk = r >> 7, n = r & 127;
    const int kt = k0 >> 6, kk = k0 & 63;
    const size_t base = (size_t)(nblk * NKT + kt) * TILE_HALVES + swz(n, kk);
    *(half4*)&img[base] = h;
    *(half4*)&img[base + BN * BK] = l;
}

// ---------------------------------------------------------------------------
// Gate GEMM via fp16-split 3-product MFMA.
//   x = xh + xl (fp16 RNE), logit = sum xh*wh + xh*wl + xl*wh  (fp32 acc)
// FAST=true : B from pre-swizzled Wimg (raw float4 copy staging); split-K
//             partials stored PLAIN to P[kz][t][e].
// FAST=false: inline W convert + atomicAdd into OUT (zero-init'd) fallback.
// ---------------------------------------------------------------------------
template <bool FAST>
__global__ __launch_bounds__(256, 4) void gate_gemm_kernel(
    const float* __restrict__ X, const float* __restrict__ W,
    const _Float16* __restrict__ Wimg, float* __restrict__ OUT)
{
    __shared__ _Float16 Ah[BM * BK], Al[BM * BK];   // 4 KB + 4 KB
    __shared__ _Float16 Bhl[TILE_HALVES];           // 32 KB (hi | lo)
    _Float16* __restrict__ Bh = Bhl;
    _Float16* __restrict__ Bl = Bhl + BN * BK;

    const int tid = threadIdx.x;
    const int nb  = blockIdx.x * BN;
    const int mb  = blockIdx.y * BM;
    const int kz  = blockIdx.z;
    const int kb  = kz * KPB;

    // A staging map: 32x64 fp32 -> 2 float4/thread (8 k per thread)
    const int am = tid & 31, ak = (tid >> 5) << 3;
    const float* Aptr = X + (size_t)(mb + am) * HIDDEN + kb + ak;

    const float4* Bimg = FAST
        ? (const float4*)(Wimg + (size_t)(blockIdx.x * NKT + kz * NT) * TILE_HALVES)
        : nullptr;
    // B fallback: 128x64 fp32 -> 8 float4/thread
    const int bn = tid & 127, bk = (tid >> 7) << 5;
    const float* Bptr = W + (size_t)(nb + bn) * HIDDEN + kb + bk;

    float4 av[2], bv[8];
#pragma unroll
    for (int q = 0; q < 2; q++) av[q] = *(const float4*)(Aptr + q * 4);
    if (FAST) {
#pragma unroll
        for (int c = 0; c < 8; c++) bv[c] = Bimg[c * 256 + tid];
    } else {
#pragma unroll
        for (int q = 0; q < 8; q++) bv[q] = *(const float4*)(Bptr + q * 4);
    }

    // wave tiling: 4 waves in n; wave tile 32m x 32n
    const int lane = tid & 63, wave = tid >> 6;
    const int wn = wave * 32;
    const int fr = lane & 15, quad = lane >> 4;

    floatx4 acc[2][2];
#pragma unroll
    for (int i = 0; i < 2; i++)
#pragma unroll
        for (int j = 0; j < 2; j++) acc[i][j] = floatx4{0.f, 0.f, 0.f, 0.f};

    float4* BLDS = (float4*)Bhl;   // linear float4 view for raw-copy staging

    for (int t = 0; t < NT; t++) {
        __syncthreads();   // prev tile's frag reads done
#pragma unroll
        for (int q = 0; q < 2; q++) cvt_store(Ah, Al, am, ak + q * 4, av[q]);
        if (FAST) {
#pragma unroll
            for (int c = 0; c < 8; c++) BLDS[c * 256 + tid] = bv[c];
        } else {
#pragma unroll
            for (int q = 0; q < 8; q++) cvt_store(Bh, Bl, bn, bk + q * 4, bv[q]);
        }
        __syncthreads();   // LDS ready

        if (t + 1 < NT) {  // prefetch next tile; MFMA below hides latency
#pragma unroll
            for (int q = 0; q < 2; q++)
                av[q] = *(const float4*)(Aptr + (t + 1) * BK + q * 4);
            if (FAST) {
#pragma unroll
                for (int c = 0; c < 8; c++)
                    bv[c] = Bimg[(t + 1) * TILE_F4 + c * 256 + tid];
            } else {
#pragma unroll
                for (int q = 0; q < 8; q++)
                    bv[q] = *(const float4*)(Bptr + (t + 1) * BK + q * 4);
            }
        }

#pragma unroll
        for (int ks = 0; ks < 2; ks++) {
            half8 a_h[2], a_l[2], b_h[2], b_l[2];
            const int kk = ks * 32 + quad * 8;
#pragma unroll
            for (int i = 0; i < 2; i++) {
                const int a = swz(i * 16 + fr, kk);
                a_h[i] = *(half8*)&Ah[a];
                a_l[i] = *(half8*)&Al[a];
            }
#pragma unroll
            for (int j = 0; j < 2; j++) {
                const int a = swz(wn + j * 16 + fr, kk);
                b_h[j] = *(half8*)&Bh[a];
                b_l[j] = *(half8*)&Bl[a];
            }
#pragma unroll
            for (int i = 0; i < 2; i++)
#pragma unroll
                for (int j = 0; j < 2; j++) {
                    acc[i][j] = __builtin_amdgcn_mfma_f32_16x16x32_f16(
                        a_l[i], b_h[j], acc[i][j], 0, 0, 0);
                    acc[i][j] = __builtin_amdgcn_mfma_f32_16x16x32_f16(
                        a_h[i], b_l[j], acc[i][j], 0, 0, 0);
                    acc[i][j] = __builtin_amdgcn_mfma_f32_16x16x32_f16(
                        a_h[i], b_h[j], acc[i][j], 0, 0, 0);
                }
        }
    }

    // epilogue: D row = token (quad*4+reg), col = expert (lane&15).
    if (FAST) {
        float* P = OUT + (size_t)kz * TOKENS * NEXPERT;
#pragma unroll
        for (int i = 0; i < 2; i++)
#pragma unroll
            for (int j = 0; j < 2; j++) {
                const int col = nb + wn + j * 16 + fr;
#pragma unroll
                for (int r = 0; r < 4; r++) {
                    const int row = mb + i * 16 + quad * 4 + r;
                    P[(size_t)row * NEXPERT + col] = acc[i][j][r];
                }
            }
    } else {
#pragma unroll
        for (int i = 0; i < 2; i++)
#pragma unroll
            for (int j = 0; j < 2; j++) {
                const int col = nb + wn + j * 16 + fr;
#pragma unroll
                for (int r = 0; r < 4; r++) {
                    const int row = mb + i * 16 + quad * 4 + r;
                    atomicAdd(&OUT[(size_t)row * NEXPERT + col], acc[i][j][r]);
                }
            }
    }
}

// ---------------------------------------------------------------------------
// Routing: one wave per token. Sums NP split-K partials, applies sigmoid,
// then exact jax top-k semantics (lowest-index tie-breaks). Writes OUT.
// NP=1 with P==OUT handles the fallback (in-place, own-token only: safe).
// ---------------------------------------------------------------------------
template <int NP>
__global__ __launch_bounds__(256) void route_kernel(
    const float* __restrict__ P, float* __restrict__ OUT,
    const float* __restrict__ bias)
{
    const int lane = threadIdx.x & 63;
    const int wave = threadIdx.x >> 6;
    const int t    = blockIdx.x * 4 + wave;

    float4 lg4 = *(const float4*)&P[(size_t)t * NEXPERT + lane * 4];
#pragma unroll
    for (int p = 1; p < NP; p++) {
        const float4 q = *(const float4*)
            &P[((size_t)p * TOKENS + t) * NEXPERT + lane * 4];
        lg4.x += q.x; lg4.y += q.y; lg4.z += q.z; lg4.w += q.w;
    }
    const float4 b4 = *(const float4*)&bias[lane * 4];
    float sc[4];
    sc[0] = 1.0f / (1.0f + expf(-lg4.x));
    sc[1] = 1.0f / (1.0f + expf(-lg4.y));
    sc[2] = 1.0f / (1.0f + expf(-lg4.z));
    sc[3] = 1.0f / (1.0f + expf(-lg4.w));
    float swb[4] = { sc[0] + b4.x, sc[1] + b4.y, sc[2] + b4.z, sc[3] + b4.w };

    // per-lane top-2 of 4
    float m1 = -INFINITY, m2 = -INFINITY;
#pragma unroll
    for (int j = 0; j < 4; j++) {
        const float v = swb[j];
        if (v > m1)      { m2 = m1; m1 = v; }
        else if (v > m2) { m2 = v; }
    }
    // merge across the 8 lanes of my group
#pragma unroll
    for (int s = 1; s < 8; s <<= 1) {
        const float o1 = __shfl_xor(m1, s, 64);
        const float o2 = __shfl_xor(m2, s, 64);
        const float hi = fmaxf(m1, o1);
        const float lo = fminf(m1, o1);
        m2 = fmaxf(lo, fmaxf(m2, o2));
        m1 = hi;
    }
    const float gs = m1 + m2;

    // top-4 groups by rank (tie -> lower group index)
    float gsc[NGROUP];
#pragma unroll
    for (int g = 0; g < NGROUP; g++) gsc[g] = __shfl(gs, g * 8, 64);
    const int myg = lane >> 3;
    int rank = 0;
#pragma unroll
    for (int g = 0; g < NGROUP; g++)
        rank += (gsc[g] > gs) || (gsc[g] == gs && g < myg);
    const bool kept = (rank < TOPKG);

    float v[4];
#pragma unroll
    for (int j = 0; j < 4; j++) v[j] = kept ? swb[j] : 0.0f;

    // top-8 experts: 8 rounds of wave argmax (lowest idx on ties)
    float sum = 0.0f;
    int selmask = 0;
    for (int r = 0; r < TOPK; r++) {
        float bv = -INFINITY;
        int   bi = 0x7fffffff;
#pragma unroll
        for (int j = 0; j < 4; j++) {
            const bool avail = ((selmask >> j) & 1) == 0;
            if (avail && v[j] > bv) { bv = v[j]; bi = lane * 4 + j; }
        }
#pragma unroll
        for (int s = 1; s < 64; s <<= 1) {
            const float ov = __shfl_xor(bv, s, 64);
            const int   oi = __shfl_xor(bi, s, 64);
            if (ov > bv || (ov == bv && oi < bi)) { bv = ov; bi = oi; }
        }
        const int wl = bi >> 2, wj = bi & 3;
        const float mysc = (wj == 0) ? sc[0] : (wj == 1) ? sc[1]
                         : (wj == 2) ? sc[2] : sc[3];
        sum += __shfl(mysc, wl, 64);
        if (lane == wl) selmask |= (1 << wj);
    }

    const float rcp = SCALE / (sum + 1e-20f);
    float4 o;
    o.x = (selmask & 1) ? sc[0] * rcp : 0.0f;
    o.y = (selmask & 2) ? sc[1] * rcp : 0.0f;
    o.z = (selmask & 4) ? sc[2] * rcp : 0.0f;
    o.w = (selmask & 8) ? sc[3] * rcp : 0.0f;
    *(float4*)&OUT[(size_t)t * NEXPERT + lane * 4] = o;
}

extern "C" void kernel_launch(void* const* d_in, const int* in_sizes, int n_in,
                              void* d_out, int out_size, void* d_ws, size_t ws_size,
                              hipStream_t stream) {
    const float* X    = (const float*)d_in[0];   // [8192, 7168]
    const float* W    = (const float*)d_in[1];   // [256, 7168]
    const float* bias = (const float*)d_in[2];   // [256]
    float* out = (float*)d_out;                  // [8192, 256]

    dim3 ggrid(NEXPERT / BN, TOKENS / BM, KSPLIT);   // (2, 256, 2)
    if (ws_size >= WIMG_BYTES + PART_BYTES) {
        _Float16* wimg = (_Float16*)d_ws;
        float* P = (float*)((char*)d_ws + WIMG_BYTES);
        wsplit_kernel<<<(NEXPERT * HIDDEN / 4) / 256, 256, 0, stream>>>(W, wimg);
        gate_gemm_kernel<true><<<ggrid, 256, 0, stream>>>(X, W, wimg, P);
        route_kernel<KSPLIT><<<TOKENS / 4, 256, 0, stream>>>(P, out, bias);
    } else {
        zero_kernel<<<(TOKENS * NEXPERT / 4) / 256, 256, 0, stream>>>(out);
        gate_gemm_kernel<false><<<ggrid, 256, 0, stream>>>(X, W, nullptr, out);
        route_kernel<1><<<TOKENS / 4, 256, 0, stream>>>(out, out, bias);
    }
}

// Round 7
// 374.483 us; speedup vs baseline: 2.5782x; 2.5782x over previous
//
#include <hip/hip_runtime.h>
#include <math.h>

#define TOKENS   8192
#define HIDDEN   7168
#define NEXPERT  256
#define NGROUP   8
#define TOPKG    4
#define TOPK     8
#define SCALE    2.5f

// GEMM: 128 tokens x 128 experts per block, BK=32, split-K 4 via atomicAdd
// into d_out (R3-proven: atomic accumulation to d_out = ~16 MB HBM writes;
// the R4-R6 write blowup tracked d_ws reads, NOT atomics -> no d_ws here).
// LDS double-buffered: 2 x (A 18K + B 18K) = 72 KB -> 2 blocks/CU, grid 512.
#define BM 128
#define BN 128
#define BK 32
#define KSPLIT 4
#define KPB (HIDDEN / KSPLIT)   // 1792
#define NT  (KPB / BK)          // 56

// LDS layout (halves): addr(row,k,hl) = row*72 + (k>>3)*16 + hl*8 + (k&7).
// Row stride 72 halves = 144 B: 16B-aligned b128 frags; frag-read banks
// cycle (row*36)%32 with period 8 -> <=2-way aliasing (free, m136).
#define RSTR 72

typedef _Float16 half8 __attribute__((ext_vector_type(8)));
typedef _Float16 half4 __attribute__((ext_vector_type(4)));
typedef float    floatx4 __attribute__((ext_vector_type(4)));

// fp32 -> fp16 hi/lo split, store h4 at octet +0..7, l4 at +8..15
__device__ __forceinline__ void cvt_store(_Float16* __restrict__ H,
                                          int row, int k0, float4 v) {
    half4 h, l;
    h[0] = (_Float16)v.x; h[1] = (_Float16)v.y;
    h[2] = (_Float16)v.z; h[3] = (_Float16)v.w;
    l[0] = (_Float16)(v.x - (float)h[0]);
    l[1] = (_Float16)(v.y - (float)h[1]);
    l[2] = (_Float16)(v.z - (float)h[2]);
    l[3] = (_Float16)(v.w - (float)h[3]);
    const int base = row * RSTR + ((k0 >> 3) << 4) + (k0 & 7);
    *(half4*)&H[base]     = h;
    *(half4*)&H[base + 8] = l;
}

// ---------------------------------------------------------------------------
// zero d_out (poisoned 0xAA each iteration; atomic accumulation needs 0 init)
// ---------------------------------------------------------------------------
__global__ __launch_bounds__(256) void zero_kernel(float* __restrict__ O) {
    const int i = blockIdx.x * 256 + threadIdx.x;
    *(float4*)&O[(size_t)i * 4] = float4{0.f, 0.f, 0.f, 0.f};
}

// ---------------------------------------------------------------------------
// Gate GEMM via fp16-split 3-product MFMA (proven bit-exact through routing):
//   x = xh + xl (fp16 RNE), logit = sum xh*wh + xh*wl + xl*wh  (fp32 acc)
// Double-buffered LDS, one barrier per K-tile; atomicAdd epilogue to OUT.
// ---------------------------------------------------------------------------
__global__ __launch_bounds__(256, 2) void gate_gemm_kernel(
    const float* __restrict__ X, const float* __restrict__ W,
    float* __restrict__ OUT)
{
    __shared__ _Float16 Ab[2][BM * RSTR];   // 2 x 18 KB
    __shared__ _Float16 Bb[2][BN * RSTR];   // 2 x 18 KB  -> 72 KB total

    const int tid = threadIdx.x;
    const int nb  = blockIdx.x * BN;
    const int mb  = blockIdx.y * BM;
    const int kb  = blockIdx.z * KPB;

    // staging map: 128x32 tile = 1024 float4; thread t takes f = q*256+t,
    // q=0..3 -> row = q*32 + (t>>3), k0 = (t&7)*4
    const int srow = tid >> 3;            // 0..31 (+q*32)
    const int sk0  = (tid & 7) * 4;       // 0..28
    const float* Aptr = X + (size_t)(mb + srow) * HIDDEN + kb + sk0;
    const float* Bptr = W + (size_t)(nb + srow) * HIDDEN + kb + sk0;

    float4 av[4], bv[4];
#pragma unroll
    for (int q = 0; q < 4; q++) {
        av[q] = *(const float4*)(Aptr + (size_t)(q * 32) * HIDDEN);
        bv[q] = *(const float4*)(Bptr + (size_t)(q * 32) * HIDDEN);
    }
#pragma unroll
    for (int q = 0; q < 4; q++) {
        cvt_store(Ab[0], q * 32 + srow, sk0, av[q]);
        cvt_store(Bb[0], q * 32 + srow, sk0, bv[q]);
    }

    // 4 waves as 2x2; wave tile 64m x 64n; 4x4 16x16 frags per wave
    const int lane = tid & 63, wave = tid >> 6;
    const int wm = (wave >> 1) * 64, wn = (wave & 1) * 64;
    const int fr = lane & 15, quad = lane >> 4;

    floatx4 acc[4][4];
#pragma unroll
    for (int i = 0; i < 4; i++)
#pragma unroll
        for (int j = 0; j < 4; j++) acc[i][j] = floatx4{0.f, 0.f, 0.f, 0.f};

    for (int t = 0; t < NT; t++) {
        // issue next tile's global loads first; MFMA below hides latency
        if (t + 1 < NT) {
            const int o = (t + 1) * BK;
#pragma unroll
            for (int q = 0; q < 4; q++) {
                av[q] = *(const float4*)(Aptr + o + (size_t)(q * 32) * HIDDEN);
                bv[q] = *(const float4*)(Bptr + o + (size_t)(q * 32) * HIDDEN);
            }
        }

        __syncthreads();   // buf[t&1] fully staged; other buf free to write

        const _Float16* __restrict__ Ac = Ab[t & 1];
        const _Float16* __restrict__ Bc = Bb[t & 1];

        half8 ah[4], al[4];
#pragma unroll
        for (int i = 0; i < 4; i++) {
            const int a = (wm + i * 16 + fr) * RSTR + quad * 16;
            ah[i] = *(const half8*)&Ac[a];
            al[i] = *(const half8*)&Ac[a + 8];
        }
#pragma unroll
        for (int j = 0; j < 4; j++) {
            const int b = (wn + j * 16 + fr) * RSTR + quad * 16;
            const half8 bh = *(const half8*)&Bc[b];
            const half8 bl = *(const half8*)&Bc[b + 8];
#pragma unroll
            for (int i = 0; i < 4; i++) {
                acc[i][j] = __builtin_amdgcn_mfma_f32_16x16x32_f16(
                    al[i], bh, acc[i][j], 0, 0, 0);
                acc[i][j] = __builtin_amdgcn_mfma_f32_16x16x32_f16(
                    ah[i], bl, acc[i][j], 0, 0, 0);
                acc[i][j] = __builtin_amdgcn_mfma_f32_16x16x32_f16(
                    ah[i], bh, acc[i][j], 0, 0, 0);
            }
        }

        // stage next tile into the other buffer (overlaps this tile's MFMA)
        if (t + 1 < NT) {
            _Float16* An = Ab[(t + 1) & 1];
            _Float16* Bn = Bb[(t + 1) & 1];
#pragma unroll
            for (int q = 0; q < 4; q++) {
                cvt_store(An, q * 32 + srow, sk0, av[q]);
                cvt_store(Bn, q * 32 + srow, sk0, bv[q]);
            }
        }
    }

    // epilogue: D row = token (quad*4+reg), col = expert (lane&15);
    // split-K accumulation via atomicAdd (R3-measured: ~16 MB HBM writes)
#pragma unroll
    for (int i = 0; i < 4; i++)
#pragma unroll
        for (int j = 0; j < 4; j++) {
            const int col = nb + wn + j * 16 + fr;
#pragma unroll
            for (int r = 0; r < 4; r++) {
                const int row = mb + wm + i * 16 + quad * 4 + r;
                atomicAdd(&OUT[(size_t)row * NEXPERT + col], acc[i][j][r]);
            }
        }
}

// ---------------------------------------------------------------------------
// Routing: one wave per token, in-place on d_out (logits -> gate weights).
// Sigmoid fused; exact jax semantics incl. lowest-index tie-breaks.
// ---------------------------------------------------------------------------
__global__ __launch_bounds__(256) void route_kernel(
    float* __restrict__ S, const float* __restrict__ bias)
{
    const int lane = threadIdx.x & 63;
    const int wave = threadIdx.x >> 6;
    const int t    = blockIdx.x * 4 + wave;

    const float4 lg4 = *(const float4*)&S[(size_t)t * NEXPERT + lane * 4];
    const float4 b4  = *(const float4*)&bias[lane * 4];
    float sc[4];
    sc[0] = 1.0f / (1.0f + expf(-lg4.x));
    sc[1] = 1.0f / (1.0f + expf(-lg4.y));
    sc[2] = 1.0f / (1.0f + expf(-lg4.z));
    sc[3] = 1.0f / (1.0f + expf(-lg4.w));
    float swb[4] = { sc[0] + b4.x, sc[1] + b4.y, sc[2] + b4.z, sc[3] + b4.w };

    // per-lane top-2 of 4
    float m1 = -INFINITY, m2 = -INFINITY;
#pragma unroll
    for (int j = 0; j < 4; j++) {
        const float v = swb[j];
        if (v > m1)      { m2 = m1; m1 = v; }
        else if (v > m2) { m2 = v; }
    }
    // merge across the 8 lanes of my group
#pragma unroll
    for (int s = 1; s < 8; s <<= 1) {
        const float o1 = __shfl_xor(m1, s, 64);
        const float o2 = __shfl_xor(m2, s, 64);
        const float hi = fmaxf(m1, o1);
        const float lo = fminf(m1, o1);
        m2 = fmaxf(lo, fmaxf(m2, o2));
        m1 = hi;
    }
    const float gs = m1 + m2;

    // top-4 groups by rank (tie -> lower group index)
    float gsc[NGROUP];
#pragma unroll
    for (int g = 0; g < NGROUP; g++) gsc[g] = __shfl(gs, g * 8, 64);
    const int myg = lane >> 3;
    int rank = 0;
#pragma unroll
    for (int g = 0; g < NGROUP; g++)
        rank += (gsc[g] > gs) || (gsc[g] == gs && g < myg);
    const bool kept = (rank < TOPKG);

    float v[4];
#pragma unroll
    for (int j = 0; j < 4; j++) v[j] = kept ? swb[j] : 0.0f;

    // top-8 experts: 8 rounds of wave argmax (lowest idx on ties)
    float sum = 0.0f;
    int selmask = 0;
    for (int r = 0; r < TOPK; r++) {
        float bv = -INFINITY;
        int   bi = 0x7fffffff;
#pragma unroll
        for (int j = 0; j < 4; j++) {
            const bool avail = ((selmask >> j) & 1) == 0;
            if (avail && v[j] > bv) { bv = v[j]; bi = lane * 4 + j; }
        }
#pragma unroll
        for (int s = 1; s < 64; s <<= 1) {
            const float ov = __shfl_xor(bv, s, 64);
            const int   oi = __shfl_xor(bi, s, 64);
            if (ov > bv || (ov == bv && oi < bi)) { bv = ov; bi = oi; }
        }
        const int wl = bi >> 2, wj = bi & 3;
        const float mysc = (wj == 0) ? sc[0] : (wj == 1) ? sc[1]
                         : (wj == 2) ? sc[2] : sc[3];
        sum += __shfl(mysc, wl, 64);
        if (lane == wl) selmask |= (1 << wj);
    }

    const float rcp = SCALE / (sum + 1e-20f);
    float4 o;
    o.x = (selmask & 1) ? sc[0] * rcp : 0.0f;
    o.y = (selmask & 2) ? sc[1] * rcp : 0.0f;
    o.z = (selmask & 4) ? sc[2] * rcp : 0.0f;
    o.w = (selmask & 8) ? sc[3] * rcp : 0.0f;
    *(float4*)&S[(size_t)t * NEXPERT + lane * 4] = o;
}

extern "C" void kernel_launch(void* const* d_in, const int* in_sizes, int n_in,
                              void* d_out, int out_size, void* d_ws, size_t ws_size,
                              hipStream_t stream) {
    const float* X    = (const float*)d_in[0];   // [8192, 7168]
    const float* W    = (const float*)d_in[1];   // [256, 7168]
    const float* bias = (const float*)d_in[2];   // [256]
    float* out = (float*)d_out;                  // [8192, 256]
    (void)d_ws; (void)ws_size;   // deliberately unused: d_ws streaming caused
                                 // 0.7-0.8 B of HBM writes per byte read (R4-R6)

    zero_kernel<<<(TOKENS * NEXPERT / 4) / 256, 256, 0, stream>>>(out);
    dim3 ggrid(NEXPERT / BN, TOKENS / BM, KSPLIT);   // (2, 64, 4) = 512 blocks
    gate_gemm_kernel<<<ggrid, 256, 0, stream>>>(X, W, out);
    route_kernel<<<TOKENS / 4, 256, 0, stream>>>(out, bias);
}